// Round 1
// 784.203 us; speedup vs baseline: 1.0372x; 1.0372x over previous
//
#include <hip/hip_runtime.h>
#include <hip/hip_bf16.h>

// ---------------------------------------------------------------------------
// QuadraticGNN: 3x ResGatedGraphConv (ReLU gate, LeakyReLU 0.01, linear Wl)
//               -> global mean pool (32 graphs) -> 5-layer MLP with BN.
// Round 13:
//   - R12 gate gemms were register-occupancy bound: 76 VGPR + 64 AGPR
//     (unified file) = 140 > 128 -> 2 waves/SIMD (21% occ), 1.96 TB/s
//     effective. Now 512-thread / 8-wave blocks, RT=2 (32 AGPR), and
//     __launch_bounds__(NT,4) -> 4 waves/SIMD = 16 waves/CU.
//   - fp32 Sagg eliminated. Gate gemm writes all 256 cols (K|Q|V|S) bf16
//     to Gbf[N][256]; gathers seed from col 192 and emit bf16 pre-acts to
//     Abf; Wl gemms stage A as bf16+leaky (AMODE=2). Saves ~230 MB HBM.
//   - Error budget: Wl gemms already rounded A to bf16 for MFMA, so the
//     bf16 seed/pre-act adds only per-node uncorrelated rounding that the
//     pool attenuates ~56x.
// ---------------------------------------------------------------------------

#define GN_N 100000
#define GN_E 300000
#define GN_G 32

typedef __attribute__((ext_vector_type(8))) short short8;
typedef __attribute__((ext_vector_type(4))) float floatx4;

__device__ inline ushort f2bf_rne(float f) {
    unsigned u = __float_as_uint(f);
    unsigned r = u + 0x7fffu + ((u >> 16) & 1u);
    return (ushort)(r >> 16);
}
__device__ inline float bf2f(ushort h) { return __uint_as_float(((unsigned)h) << 16); }

// W-array layout (ushort offsets), k-major [col][K] per segment.
#define WOFF_L2   32768
#define WOFF_L3   65536
#define WOFF_WL1  196608
#define WOFF_WL2  200704
#define W_TOTAL   217088

struct WSrc {
    const float* Wg[3][4];
    const float* Wl[2];
    const float* bg[3][4];
};

__global__ void wconv(WSrc S, ushort* __restrict__ hi, ushort* __restrict__ lo,
                      float* __restrict__ biascat)
{
    int id = blockIdx.x * 256 + threadIdx.x;
    if (id < 196608) {
        int l, base, ci, co;
        if (id < 32768)      { l = 0; base = 0;        ci = 128; co = 64;  }
        else if (id < 65536) { l = 1; base = WOFF_L2;  ci = 64;  co = 128; }
        else                 { l = 2; base = WOFF_L3;  ci = 128; co = 256; }
        int r  = id - base;
        int g  = r / (co * ci);
        int r2 = r - g * co * ci;
        int c  = r2 / ci;
        int k  = r2 - c * ci;
        float v = S.Wg[l][g][k * co + c];
        int ch  = c >> 6;
        int colIdx = (g << 6) + (c & 63);
        int dst = base + ch * (256 * ci) + colIdx * ci + k;
        ushort h = f2bf_rne(v);
        hi[dst] = h; lo[dst] = f2bf_rne(v - bf2f(h));
    } else if (id < 196608 + 4096) {
        int r = id - 196608;
        int c = r >> 6, k = r & 63;
        float v = S.Wl[0][k * 64 + c];
        int dst = WOFF_WL1 + c * 64 + k;
        ushort h = f2bf_rne(v);
        hi[dst] = h; lo[dst] = f2bf_rne(v - bf2f(h));
    } else if (id < W_TOTAL) {
        int r = id - WOFF_WL2;
        int c = r >> 7, k2 = r & 127;
        float v = S.Wl[1][k2 * 128 + c];
        int dst = WOFF_WL2 + c * 128 + k2;
        ushort h = f2bf_rne(v);
        hi[dst] = h; lo[dst] = f2bf_rne(v - bf2f(h));
    } else if (id < W_TOTAL + 1792) {
        int i = id - W_TOTAL;
        int chunk = i >> 8, c = i & 255;
        int g = c >> 6, cc = c & 63;
        const int ltab[7] = {0, 1, 1, 2, 2, 2, 2};
        const int ctab[7] = {0, 0, 64, 0, 64, 128, 192};
        biascat[i] = S.bg[ltab[chunk]][g][ctab[chunk] + cc];
    }
}

// x (fp32 [N][128]) -> bf16 [N][128]
__global__ void aconv(const float* __restrict__ A, ushort* __restrict__ O)
{
    int id = blockIdx.x * 256 + threadIdx.x;
    if (id >= GN_N * 16) return;
    int r = id >> 4, cc = id & 15;
    const float* src = A + (size_t)r * 128 + cc * 8;
    short8 h;
    #pragma unroll
    for (int j = 0; j < 8; ++j) h[j] = (short)f2bf_rne(src[j]);
    *(short8*)&O[(size_t)r * 128 + cc * 8] = h;
}

// GEMM: 128 rows x BC cols per block. A bf16; AMODE=0 copy-stage,
// AMODE=2 bf16 + leaky(0.01) stage. B hi/lo: 2 MFMAs per tile.
// Output: bf16 stores to Obf (ldo). BC=128 -> 512 threads (8 waves, 32x64
// per wave, 32 AGPR); BC=64 -> 256 threads (4 waves, 32x64 per wave).
template<int BC, int AMODE>
__global__ __launch_bounds__((BC == 128) ? 512 : 256, 4) void gemm2(
    const ushort* __restrict__ Aptr, int lda,
    const ushort* __restrict__ Bh, const ushort* __restrict__ Bl,
    const float* __restrict__ bias,
    ushort* __restrict__ Obf, int ldo,
    int K)
{
    constexpr int NT = (BC == 128) ? 512 : 256;
    constexpr int ST = 34;    // LDS row stride (ushorts): 17 words, odd
    __shared__ ushort sA[128 * ST];
    __shared__ ushort sBh[BC * ST], sBl[BC * ST];

    const int tid  = threadIdx.x;
    const int w    = tid >> 6, lane = tid & 63;
    const int m    = lane & 15, quad = lane >> 4;
    const int row0 = blockIdx.x * 128;
    const int col0 = blockIdx.y * BC;
    const int wr   = (BC == 128) ? (w >> 1) * 32 : w * 32;
    const int wc   = (BC == 128) ? (w & 1) * 64 : 0;

    floatx4 acc[2][4];
    #pragma unroll
    for (int i = 0; i < 2; ++i)
        #pragma unroll
        for (int j = 0; j < 4; ++j) acc[i][j] = (floatx4){0.f, 0.f, 0.f, 0.f};

    for (int k0 = 0; k0 < K; k0 += 32) {
        // ---- stage A ----
        if constexpr (NT == 512) {
            const int ar = tid >> 2, ak = (tid & 3) * 8;
            const int arow = row0 + ar;
            short8 a0;
            if (arow < GN_N) {
                const ushort* ap = Aptr + (size_t)arow * lda + k0 + ak;
                a0 = *(const short8*)ap;
                if constexpr (AMODE == 2) {
                    #pragma unroll
                    for (int j = 0; j < 8; ++j) {
                        float f = bf2f((ushort)a0[j]);
                        f = f > 0.f ? f : 0.01f * f;
                        a0[j] = (short)f2bf_rne(f);
                    }
                }
            } else {
                #pragma unroll
                for (int j = 0; j < 8; ++j) a0[j] = 0;
            }
            *(short8*)&sA[ar * ST + ak] = a0;
        } else {
            const int ar = tid >> 1, ak = (tid & 1) * 16;
            const int arow = row0 + ar;
            short8 a0, a1;
            if (arow < GN_N) {
                const ushort* ap = Aptr + (size_t)arow * lda + k0 + ak;
                a0 = *(const short8*)ap;
                a1 = *(const short8*)(ap + 8);
                if constexpr (AMODE == 2) {
                    #pragma unroll
                    for (int j = 0; j < 8; ++j) {
                        float f = bf2f((ushort)a0[j]); f = f > 0.f ? f : 0.01f * f;
                        a0[j] = (short)f2bf_rne(f);
                        float g = bf2f((ushort)a1[j]); g = g > 0.f ? g : 0.01f * g;
                        a1[j] = (short)f2bf_rne(g);
                    }
                }
            } else {
                #pragma unroll
                for (int j = 0; j < 8; ++j) { a0[j] = 0; a1[j] = 0; }
            }
            *(short8*)&sA[ar * ST + ak]     = a0;
            *(short8*)&sA[ar * ST + ak + 8] = a1;
        }
        // ---- stage B (NT/4 == BC in both instantiations) ----
        {
            const int col = tid >> 2, bk = (tid & 3) * 8;
            size_t off = (size_t)(col0 + col) * K + k0 + bk;
            *(short8*)&sBh[col * ST + bk] = *(const short8*)(Bh + off);
            *(short8*)&sBl[col * ST + bk] = *(const short8*)(Bl + off);
        }
        __syncthreads();
        // ---- compute: 2 MFMAs per tile ----
        short8 bhf[4], blf[4];
        #pragma unroll
        for (int ct = 0; ct < 4; ++ct) {
            bhf[ct] = *(const short8*)&sBh[(wc + ct * 16 + m) * ST + quad * 8];
            blf[ct] = *(const short8*)&sBl[(wc + ct * 16 + m) * ST + quad * 8];
        }
        #pragma unroll
        for (int rt = 0; rt < 2; ++rt) {
            short8 ahf = *(const short8*)&sA[(wr + rt * 16 + m) * ST + quad * 8];
            #pragma unroll
            for (int ct = 0; ct < 4; ++ct) {
                acc[rt][ct] = __builtin_amdgcn_mfma_f32_16x16x32_bf16(ahf, bhf[ct], acc[rt][ct], 0, 0, 0);
                acc[rt][ct] = __builtin_amdgcn_mfma_f32_16x16x32_bf16(ahf, blf[ct], acc[rt][ct], 0, 0, 0);
            }
        }
        __syncthreads();
    }

    #pragma unroll
    for (int rt = 0; rt < 2; ++rt) {
        #pragma unroll
        for (int ct = 0; ct < 4; ++ct) {
            int ocol = col0 + wc + ct * 16 + m;
            float bb = bias[ocol];
            #pragma unroll
            for (int reg = 0; reg < 4; ++reg) {
                int orow = row0 + wr + rt * 16 + quad * 4 + reg;
                if (orow >= GN_N) continue;
                Obf[(size_t)orow * ldo + ocol] = f2bf_rne(acc[rt][ct][reg] + bb);
            }
        }
    }
}

// ---------------- CSR build ----------------
__global__ void zero_int(int* p, int n)
{
    int i = blockIdx.x * 256 + threadIdx.x;
    if (i < n) p[i] = 0;
}

__global__ void hist_kernel(const int* __restrict__ dst, int* __restrict__ deg)
{
    int e = blockIdx.x * 256 + threadIdx.x;
    if (e < GN_E) atomicAdd(&deg[dst[e]], 1);
}

__global__ void scan1(const int* __restrict__ deg, int* __restrict__ rp, int* __restrict__ bsums)
{
    __shared__ int s[256];
    int b = blockIdx.x, t = threadIdx.x;
    int i = b * 256 + t;
    int v = (i < GN_N) ? deg[i] : 0;
    s[t] = v;
    __syncthreads();
    for (int off = 1; off < 256; off <<= 1) {
        int x = (t >= off) ? s[t - off] : 0;
        __syncthreads();
        s[t] += x;
        __syncthreads();
    }
    if (i < GN_N) rp[i] = s[t] - v;
    if (t == 255) bsums[b] = s[255];
}

__global__ __launch_bounds__(512) void scan2(int* bsums, int nb)
{
    __shared__ int s[512];
    int t = threadIdx.x;
    int v = (t < nb) ? bsums[t] : 0;
    s[t] = v;
    __syncthreads();
    for (int off = 1; off < 512; off <<= 1) {
        int x = (t >= off) ? s[t - off] : 0;
        __syncthreads();
        s[t] += x;
        __syncthreads();
    }
    if (t < nb) bsums[t] = s[t] - v;
}

__global__ void scan3(const int* __restrict__ bsums, int* __restrict__ rp, int* __restrict__ cursor)
{
    int b = blockIdx.x, t = threadIdx.x;
    int i = b * 256 + t;
    if (i < GN_N) {
        int v = rp[i] + bsums[b];
        rp[i] = v; cursor[i] = v;
    }
    if (i == 0) rp[GN_N] = GN_E;
}

__global__ void scatter_kernel(
    const int* __restrict__ src, const int* __restrict__ dst,
    int* __restrict__ cursor, int* __restrict__ elist)
{
    int e = blockIdx.x * 256 + threadIdx.x;
    if (e >= GN_E) return;
    int d = dst[e];
    int pos = atomicAdd(&cursor[d], 1);
    elist[pos] = src[e];
}

__global__ void bounds_kernel(const int* __restrict__ batch, int* __restrict__ se)
{
    int i = blockIdx.x * 256 + threadIdx.x;
    if (i >= GN_N) return;
    int g = batch[i];
    if (i == 0 || batch[i - 1] != g) se[g] = i;
    if (i == GN_N - 1 || batch[i + 1] != g) se[32 + g] = i + 1;
}

__global__ void cnt_kernel(const int* __restrict__ se, float* __restrict__ cnt)
{
    int g = threadIdx.x;
    if (g < GN_G) cnt[g] = (float)(se[32 + g] - se[g]);
}

// Gbf[N][256] = K|Q|V|S (bf16). acc seeds from S (col 192); out_i =
// S_i + sum relu(K[i]+Q[j])*V[j] written bf16 to Abf (ald/aoff). 4 nodes/wave.
__global__ __launch_bounds__(256) void edge_gather_w(
    const ushort* __restrict__ Gbf, ushort* __restrict__ Abf, int ald, int aoff,
    const int* __restrict__ row_ptr, const int* __restrict__ elist)
{
    int w = threadIdx.x >> 6, c = threadIdx.x & 63;
    int n0 = blockIdx.x * 16 + w * 4;

    float k[4], acc[4];
    int beg[4], end[4];
    #pragma unroll
    for (int j = 0; j < 4; ++j) {
        int node = n0 + j;
        bool ok = node < GN_N;
        int nd = ok ? node : 0;
        beg[j] = row_ptr[nd];
        end[j] = ok ? row_ptr[nd + 1] : beg[j];
        k[j]   = bf2f(Gbf[(size_t)nd * 256 + c]);
        acc[j] = bf2f(Gbf[(size_t)nd * 256 + 192 + c]);
    }
    int s[16];
    #pragma unroll
    for (int j = 0; j < 4; ++j) {
        #pragma unroll
        for (int e = 0; e < 4; ++e) {
            int idx = beg[j] + e;
            s[j * 4 + e] = elist[idx < end[j] ? idx : 0];
        }
    }
    float q[16], v[16];
    #pragma unroll
    for (int je = 0; je < 16; ++je) {
        q[je] = bf2f(Gbf[(size_t)s[je] * 256 + 64 + c]);
        v[je] = bf2f(Gbf[(size_t)s[je] * 256 + 128 + c]);
    }
    #pragma unroll
    for (int j = 0; j < 4; ++j) {
        #pragma unroll
        for (int e = 0; e < 4; ++e) {
            if (beg[j] + e < end[j]) {
                float gt = k[j] + q[j * 4 + e];
                if (gt > 0.f) acc[j] += gt * v[j * 4 + e];
            }
        }
    }
    #pragma unroll
    for (int j = 0; j < 4; ++j) {
        for (int i = beg[j] + 4; i < end[j]; ++i) {
            int ss = elist[i];
            float qq = bf2f(Gbf[(size_t)ss * 256 + 64 + c]);
            float vv = bf2f(Gbf[(size_t)ss * 256 + 128 + c]);
            float gt = k[j] + qq;
            if (gt > 0.f) acc[j] += gt * vv;
        }
    }
    #pragma unroll
    for (int j = 0; j < 4; ++j)
        if (n0 + j < GN_N) Abf[(size_t)(n0 + j) * ald + aoff + c] = f2bf_rne(acc[j]);
}

// Layer-3: gather + leaky + 16-node LDS reduce + run-length atomics into sums.
__global__ __launch_bounds__(256) void edge_gather_pool(
    const ushort* __restrict__ Gbf,
    const int* __restrict__ row_ptr, const int* __restrict__ elist,
    const int* __restrict__ batch,
    float* __restrict__ sums, int c0)
{
    __shared__ float red[16][64];
    __shared__ int gid[16];
    int w = threadIdx.x >> 6, c = threadIdx.x & 63;
    int n0 = blockIdx.x * 16 + w * 4;

    float k[4], acc[4];
    int beg[4], end[4];
    #pragma unroll
    for (int j = 0; j < 4; ++j) {
        int node = n0 + j;
        bool ok = node < GN_N;
        int nd = ok ? node : 0;
        beg[j] = row_ptr[nd];
        end[j] = ok ? row_ptr[nd + 1] : beg[j];
        k[j]   = bf2f(Gbf[(size_t)nd * 256 + c]);
        acc[j] = ok ? bf2f(Gbf[(size_t)nd * 256 + 192 + c]) : 0.f;
    }
    int s[16];
    #pragma unroll
    for (int j = 0; j < 4; ++j) {
        #pragma unroll
        for (int e = 0; e < 4; ++e) {
            int idx = beg[j] + e;
            s[j * 4 + e] = elist[idx < end[j] ? idx : 0];
        }
    }
    float q[16], v[16];
    #pragma unroll
    for (int je = 0; je < 16; ++je) {
        q[je] = bf2f(Gbf[(size_t)s[je] * 256 + 64 + c]);
        v[je] = bf2f(Gbf[(size_t)s[je] * 256 + 128 + c]);
    }
    #pragma unroll
    for (int j = 0; j < 4; ++j) {
        #pragma unroll
        for (int e = 0; e < 4; ++e) {
            if (beg[j] + e < end[j]) {
                float gt = k[j] + q[j * 4 + e];
                if (gt > 0.f) acc[j] += gt * v[j * 4 + e];
            }
        }
    }
    #pragma unroll
    for (int j = 0; j < 4; ++j) {
        for (int i = beg[j] + 4; i < end[j]; ++i) {
            int ss = elist[i];
            float qq = bf2f(Gbf[(size_t)ss * 256 + 64 + c]);
            float vv = bf2f(Gbf[(size_t)ss * 256 + 128 + c]);
            float gt = k[j] + qq;
            if (gt > 0.f) acc[j] += gt * vv;
        }
    }
    #pragma unroll
    for (int j = 0; j < 4; ++j) {
        float a = acc[j];
        red[w * 4 + j][c] = a > 0.f ? a : 0.01f * a;
    }
    if (c < 4) {
        int node = n0 + c;
        gid[w * 4 + c] = (node < GN_N) ? batch[node] : -1;
    }
    __syncthreads();
    if (w == 0) {
        int i = 0;
        while (i < 16) {
            int gg = gid[i];
            float sum = 0.f;
            int j = i;
            while (j < 16 && gid[j] == gg) { sum += red[j][c]; ++j; }
            if (gg >= 0) atomicAdd(&sums[gg * 256 + c0 + c], sum);
            i = j;
        }
    }
}

__global__ void zero_sums(float* sums)
{
    int i = blockIdx.x * 256 + threadIdx.x;
    if (i < GN_G * 256) sums[i] = 0.0f;
}

// One block per graph: Pl = sums[g]/cnt[g]; Pg = Pl @ Wl3 + bl3; BN-MLP chain.
__global__ __launch_bounds__(256) void mlp_kernel(
    const float* __restrict__ sums, const float* __restrict__ cnt,
    const float* __restrict__ Wl3, const float* __restrict__ bl3,
    const float* __restrict__ W1, const float* __restrict__ b1,
    const float* __restrict__ Wh, const float* __restrict__ bh,
    const float* __restrict__ Wo, const float* __restrict__ bo,
    const float* __restrict__ gamma, const float* __restrict__ beta,
    const float* __restrict__ mean, const float* __restrict__ var,
    float* __restrict__ out)
{
    __shared__ float sp[256];
    __shared__ float pg[256];
    __shared__ float h0[64], h1[64];
    const int g = blockIdx.x;
    const int t = threadIdx.x;
    const float inv = 1.0f / fmaxf(cnt[g], 1.0f);

    sp[t] = sums[g * 256 + t] * inv;
    __syncthreads();

    {
        float a0 = 0.f, a1 = 0.f, a2 = 0.f, a3 = 0.f;
        #pragma unroll 4
        for (int k = 0; k < 256; k += 4) {
            a0 += sp[k + 0] * Wl3[(k + 0) * 256 + t];
            a1 += sp[k + 1] * Wl3[(k + 1) * 256 + t];
            a2 += sp[k + 2] * Wl3[(k + 2) * 256 + t];
            a3 += sp[k + 3] * Wl3[(k + 3) * 256 + t];
        }
        pg[t] = bl3[t] + ((a0 + a1) + (a2 + a3));
    }
    __syncthreads();

    if (t < 64) {
        float a0 = 0.f, a1 = 0.f, a2 = 0.f, a3 = 0.f;
        #pragma unroll 4
        for (int k = 0; k < 256; k += 4) {
            a0 += pg[k + 0] * W1[(k + 0) * 64 + t];
            a1 += pg[k + 1] * W1[(k + 1) * 64 + t];
            a2 += pg[k + 2] * W1[(k + 2) * 64 + t];
            a3 += pg[k + 3] * W1[(k + 3) * 64 + t];
        }
        float acc = b1[t] + ((a0 + a1) + (a2 + a3));
        float sc = gamma[t] * rsqrtf(var[t] + 1e-5f);
        acc = (acc - mean[t]) * sc + beta[t];
        h0[t] = fmaxf(acc, 0.0f);
    }
    __syncthreads();

    for (int L = 0; L < 3; ++L) {
        const float* W  = Wh + L * 64 * 64;
        const float* hin  = (L & 1) ? h1 : h0;
        float*       hout = (L & 1) ? h0 : h1;
        if (t < 64) {
            const float* ga = gamma + (L + 1) * 64;
            const float* be = beta  + (L + 1) * 64;
            const float* me = mean  + (L + 1) * 64;
            const float* va = var   + (L + 1) * 64;
            float a0 = 0.f, a1 = 0.f, a2 = 0.f, a3 = 0.f;
            #pragma unroll 4
            for (int k = 0; k < 64; k += 4) {
                a0 += hin[k + 0] * W[(k + 0) * 64 + t];
                a1 += hin[k + 1] * W[(k + 1) * 64 + t];
                a2 += hin[k + 2] * W[(k + 2) * 64 + t];
                a3 += hin[k + 3] * W[(k + 3) * 64 + t];
            }
            float acc = (bh + L * 64)[t] + ((a0 + a1) + (a2 + a3));
            float sc = ga[t] * rsqrtf(va[t] + 1e-5f);
            acc = (acc - me[t]) * sc + be[t];
            hout[t] = fmaxf(acc, 0.0f);
        }
        __syncthreads();
    }

    if (t < 8) {
        const float* hf = h1;
        float acc = bo[t];
        for (int k = 0; k < 64; ++k) acc += hf[k] * Wo[k * 8 + t];
        out[g * 8 + t] = acc;
    }
}

extern "C" void kernel_launch(void* const* d_in, const int* in_sizes, int n_in,
                              void* d_out, int out_size, void* d_ws, size_t ws_size,
                              hipStream_t stream)
{
    const int N = GN_N, E = GN_E;
    const float* x          = (const float*)d_in[0];
    const int*   edge_index = (const int*)d_in[1];
    const int*   batch      = (const int*)d_in[2];
    const int*   src = edge_index;
    const int*   dst = edge_index + E;
    auto F = [&](int i) { return (const float*)d_in[i]; };

    // ---- workspace layout ----
    float* ws    = (float*)d_ws;
    float* sums  = ws;                          // 32 x 256
    float* cnt   = sums + GN_G * 256;           // 32
    float* bcat  = cnt + GN_G;                  // 7 x 256
    ushort* Whi  = (ushort*)(bcat + 1792);
    ushort* Wlo  = Whi + W_TOTAL;
    ushort* xbf  = Wlo + W_TOTAL;               // N x 128 bf16
    ushort* hAbf = xbf + (size_t)N * 128;       // N x 64 bf16
    ushort* hBbf = hAbf + (size_t)N * 64;       // N x 128 bf16
    ushort* Gbf  = hBbf + (size_t)N * 128;      // N x 256 bf16 [K|Q|V|S]
    ushort* Abf  = Gbf + (size_t)N * 256;       // N x 128 bf16 (pre-Wl acts)
    int* deg     = (int*)(Abf + (size_t)N * 128);
    int* cursor  = deg + N;
    int* row_ptr = cursor + N;                  // N+1
    int* elist   = row_ptr + (N + 1);           // E
    int* bsums   = elist + E;                   // 512
    int* se      = bsums + 512;                 // 64

    size_t need = (size_t)((char*)(se + 64) - (char*)ws);
    if (ws_size < need) return;

    // ---- CSR build + graph bounds ----
    const int eb = (E + 255) / 256;
    const int nb = (N + 255) / 256;
    zero_int<<<nb, 256, 0, stream>>>(deg, N);
    zero_int<<<1, 256, 0, stream>>>(se, 64);
    hist_kernel<<<eb, 256, 0, stream>>>(dst, deg);
    scan1<<<nb, 256, 0, stream>>>(deg, row_ptr, bsums);
    scan2<<<1, 512, 0, stream>>>(bsums, nb);
    scan3<<<nb, 256, 0, stream>>>(bsums, row_ptr, cursor);
    scatter_kernel<<<eb, 256, 0, stream>>>(src, dst, cursor, elist);
    bounds_kernel<<<nb, 256, 0, stream>>>(batch, se);
    cnt_kernel<<<1, 64, 0, stream>>>(se, cnt);

    // ---- weight + input pre-conversion ----
    WSrc S;
    for (int l = 0; l < 3; ++l) {
        int base = 3 + l * 10;
        for (int g = 0; g < 4; ++g) S.Wg[l][g] = F(base + g);
        for (int g = 0; g < 4; ++g) S.bg[l][g] = F(base + 4 + g);
    }
    S.Wl[0] = F(11); S.Wl[1] = F(21);
    wconv<<<(W_TOTAL + 1792 + 255) / 256, 256, 0, stream>>>(S, Whi, Wlo, bcat);
    aconv<<<(N * 16 + 255) / 256, 256, 0, stream>>>(x, xbf);

    zero_sums<<<(GN_G * 256 + 255) / 256, 256, 0, stream>>>(sums);

    const int rb = (N + 127) / 128;
    const int gatherBlocks = (N + 15) / 16;

    // ---- layer 1 ----
    gemm2<128, 0><<<dim3(rb, 2), 512, 0, stream>>>(
        xbf, 128, Whi, Wlo, bcat, Gbf, 256, 128);
    edge_gather_w<<<gatherBlocks, 256, 0, stream>>>(Gbf, Abf, 64, 0, row_ptr, elist);
    gemm2<64, 2><<<dim3(rb, 1), 256, 0, stream>>>(
        Abf, 64, Whi + WOFF_WL1, Wlo + WOFF_WL1, F(12), hAbf, 64, 64);

    // ---- layer 2 (2 chunks of gates, then one Wl2) ----
    for (int ch = 0; ch < 2; ++ch) {
        size_t go = WOFF_L2 + (size_t)ch * 16384;
        gemm2<128, 0><<<dim3(rb, 2), 512, 0, stream>>>(
            hAbf, 64, Whi + go, Wlo + go, bcat + (1 + ch) * 256, Gbf, 256, 64);
        edge_gather_w<<<gatherBlocks, 256, 0, stream>>>(
            Gbf, Abf, 128, ch * 64, row_ptr, elist);
    }
    gemm2<128, 2><<<dim3(rb, 1), 512, 0, stream>>>(
        Abf, 128, Whi + WOFF_WL2, Wlo + WOFF_WL2, F(22), hBbf, 128, 128);

    // ---- layer 3 (4 chunks, fused pool) ----
    for (int ch = 0; ch < 4; ++ch) {
        size_t go = WOFF_L3 + (size_t)ch * 32768;
        gemm2<128, 0><<<dim3(rb, 2), 512, 0, stream>>>(
            hBbf, 128, Whi + go, Wlo + go, bcat + (3 + ch) * 256, Gbf, 256, 128);
        edge_gather_pool<<<gatherBlocks, 256, 0, stream>>>(
            Gbf, row_ptr, elist, batch, sums, ch * 64);
    }

    mlp_kernel<<<GN_G, 256, 0, stream>>>(sums, cnt, F(31), F(32),
                                         F(33), F(34), F(35), F(36), F(37), F(38),
                                         F(39), F(40), F(41), F(42),
                                         (float*)d_out);
}

// Round 2
// 714.682 us; speedup vs baseline: 1.1381x; 1.0973x over previous
//
#include <hip/hip_runtime.h>
#include <hip/hip_bf16.h>

// ---------------------------------------------------------------------------
// QuadraticGNN: 3x ResGatedGraphConv (ReLU gate, LeakyReLU 0.01, linear Wl)
//               -> global mean pool (32 graphs) -> 5-layer MLP with BN.
// Round 14:
//   - R13 gathers were latency-bound (VGPR=40 -> compiler serialized the
//     q/v prefetch; 1.04 TB/s, 49us each). Now:
//     * Gbf packed as [K | Q0V0Q1V1.. | S] via weight-column permute in
//       wconv (gemm untouched, stores stay coalesced). Gather reads Q+V
//       as ONE aligned uint -> one 256B contiguous wave access per edge.
//     * 8-edge batch (covers ~98% of Poisson(3) nodes), all 32 elist +
//       32 qv loads independent; __launch_bounds__(256,2) so the
//       allocator keeps them in flight (~95 VGPR).
//     * Pool atomics striped 32x (sums[32][G][256], stripe=blockIdx&31);
//       mlp_kernel reduces stripes on entry.
// ---------------------------------------------------------------------------

#define GN_N 100000
#define GN_E 300000
#define GN_G 32

typedef __attribute__((ext_vector_type(8))) short short8;
typedef __attribute__((ext_vector_type(4))) float floatx4;

__device__ inline ushort f2bf_rne(float f) {
    unsigned u = __float_as_uint(f);
    unsigned r = u + 0x7fffu + ((u >> 16) & 1u);
    return (ushort)(r >> 16);
}
__device__ inline float bf2f(ushort h) { return __uint_as_float(((unsigned)h) << 16); }

// W-array layout (ushort offsets), k-major [col][K] per segment.
#define WOFF_L2   32768
#define WOFF_L3   65536
#define WOFF_WL1  196608
#define WOFF_WL2  200704
#define W_TOTAL   217088

struct WSrc {
    const float* Wg[3][4];
    const float* Wl[2];
    const float* bg[3][4];
};

__global__ void wconv(WSrc S, ushort* __restrict__ hi, ushort* __restrict__ lo,
                      float* __restrict__ biascat)
{
    int id = blockIdx.x * 256 + threadIdx.x;
    if (id < 196608) {
        int l, base, ci, co;
        if (id < 32768)      { l = 0; base = 0;        ci = 128; co = 64;  }
        else if (id < 65536) { l = 1; base = WOFF_L2;  ci = 64;  co = 128; }
        else                 { l = 2; base = WOFF_L3;  ci = 128; co = 256; }
        int r  = id - base;
        int g  = r / (co * ci);
        int r2 = r - g * co * ci;
        int c  = r2 / ci;
        int k  = r2 - c * ci;
        float v = S.Wg[l][g][k * co + c];
        int ch  = c >> 6;
        int cc  = c & 63;
        // packed col within 256-chunk: K->cc, Q->64+2cc, V->65+2cc, S->192+cc
        int colIdx = (g == 0) ? cc : (g == 3) ? (192 + cc) : (64 + 2 * cc + (g - 1));
        int dst = base + ch * (256 * ci) + colIdx * ci + k;
        ushort h = f2bf_rne(v);
        hi[dst] = h; lo[dst] = f2bf_rne(v - bf2f(h));
    } else if (id < 196608 + 4096) {
        int r = id - 196608;
        int c = r >> 6, k = r & 63;
        float v = S.Wl[0][k * 64 + c];
        int dst = WOFF_WL1 + c * 64 + k;
        ushort h = f2bf_rne(v);
        hi[dst] = h; lo[dst] = f2bf_rne(v - bf2f(h));
    } else if (id < W_TOTAL) {
        int r = id - WOFF_WL2;
        int c = r >> 7, k2 = r & 127;
        float v = S.Wl[1][k2 * 128 + c];
        int dst = WOFF_WL2 + c * 128 + k2;
        ushort h = f2bf_rne(v);
        hi[dst] = h; lo[dst] = f2bf_rne(v - bf2f(h));
    } else if (id < W_TOTAL + 1792) {
        int i = id - W_TOTAL;
        int chunk = i >> 8, p = i & 255;
        // invert the interleave map: packed pos p -> (g, cc)
        int g, cc;
        if (p < 64)       { g = 0; cc = p; }
        else if (p < 192) { g = 1 + ((p - 64) & 1); cc = (p - 64) >> 1; }
        else              { g = 3; cc = p - 192; }
        const int ltab[7] = {0, 1, 1, 2, 2, 2, 2};
        const int ctab[7] = {0, 0, 64, 0, 64, 128, 192};
        biascat[i] = S.bg[ltab[chunk]][g][ctab[chunk] + cc];
    }
}

// x (fp32 [N][128]) -> bf16 [N][128]
__global__ void aconv(const float* __restrict__ A, ushort* __restrict__ O)
{
    int id = blockIdx.x * 256 + threadIdx.x;
    if (id >= GN_N * 16) return;
    int r = id >> 4, cc = id & 15;
    const float* src = A + (size_t)r * 128 + cc * 8;
    short8 h;
    #pragma unroll
    for (int j = 0; j < 8; ++j) h[j] = (short)f2bf_rne(src[j]);
    *(short8*)&O[(size_t)r * 128 + cc * 8] = h;
}

// GEMM: 128 rows x BC cols per block. A bf16; AMODE=0 copy-stage,
// AMODE=2 bf16 + leaky(0.01) stage. B hi/lo: 2 MFMAs per tile.
// Output: bf16 stores to Obf (ldo). BC=128 -> 512 threads (8 waves, 32x64
// per wave, 32 AGPR); BC=64 -> 256 threads (4 waves, 32x64 per wave).
template<int BC, int AMODE>
__global__ __launch_bounds__((BC == 128) ? 512 : 256, 4) void gemm2(
    const ushort* __restrict__ Aptr, int lda,
    const ushort* __restrict__ Bh, const ushort* __restrict__ Bl,
    const float* __restrict__ bias,
    ushort* __restrict__ Obf, int ldo,
    int K)
{
    constexpr int NT = (BC == 128) ? 512 : 256;
    constexpr int ST = 34;    // LDS row stride (ushorts): 17 words, odd
    __shared__ ushort sA[128 * ST];
    __shared__ ushort sBh[BC * ST], sBl[BC * ST];

    const int tid  = threadIdx.x;
    const int w    = tid >> 6, lane = tid & 63;
    const int m    = lane & 15, quad = lane >> 4;
    const int row0 = blockIdx.x * 128;
    const int col0 = blockIdx.y * BC;
    const int wr   = (BC == 128) ? (w >> 1) * 32 : w * 32;
    const int wc   = (BC == 128) ? (w & 1) * 64 : 0;

    floatx4 acc[2][4];
    #pragma unroll
    for (int i = 0; i < 2; ++i)
        #pragma unroll
        for (int j = 0; j < 4; ++j) acc[i][j] = (floatx4){0.f, 0.f, 0.f, 0.f};

    for (int k0 = 0; k0 < K; k0 += 32) {
        // ---- stage A ----
        if constexpr (NT == 512) {
            const int ar = tid >> 2, ak = (tid & 3) * 8;
            const int arow = row0 + ar;
            short8 a0;
            if (arow < GN_N) {
                const ushort* ap = Aptr + (size_t)arow * lda + k0 + ak;
                a0 = *(const short8*)ap;
                if constexpr (AMODE == 2) {
                    #pragma unroll
                    for (int j = 0; j < 8; ++j) {
                        float f = bf2f((ushort)a0[j]);
                        f = f > 0.f ? f : 0.01f * f;
                        a0[j] = (short)f2bf_rne(f);
                    }
                }
            } else {
                #pragma unroll
                for (int j = 0; j < 8; ++j) a0[j] = 0;
            }
            *(short8*)&sA[ar * ST + ak] = a0;
        } else {
            const int ar = tid >> 1, ak = (tid & 1) * 16;
            const int arow = row0 + ar;
            short8 a0, a1;
            if (arow < GN_N) {
                const ushort* ap = Aptr + (size_t)arow * lda + k0 + ak;
                a0 = *(const short8*)ap;
                a1 = *(const short8*)(ap + 8);
                if constexpr (AMODE == 2) {
                    #pragma unroll
                    for (int j = 0; j < 8; ++j) {
                        float f = bf2f((ushort)a0[j]); f = f > 0.f ? f : 0.01f * f;
                        a0[j] = (short)f2bf_rne(f);
                        float g = bf2f((ushort)a1[j]); g = g > 0.f ? g : 0.01f * g;
                        a1[j] = (short)f2bf_rne(g);
                    }
                }
            } else {
                #pragma unroll
                for (int j = 0; j < 8; ++j) { a0[j] = 0; a1[j] = 0; }
            }
            *(short8*)&sA[ar * ST + ak]     = a0;
            *(short8*)&sA[ar * ST + ak + 8] = a1;
        }
        // ---- stage B (NT/4 == BC in both instantiations) ----
        {
            const int col = tid >> 2, bk = (tid & 3) * 8;
            size_t off = (size_t)(col0 + col) * K + k0 + bk;
            *(short8*)&sBh[col * ST + bk] = *(const short8*)(Bh + off);
            *(short8*)&sBl[col * ST + bk] = *(const short8*)(Bl + off);
        }
        __syncthreads();
        // ---- compute: 2 MFMAs per tile ----
        short8 bhf[4], blf[4];
        #pragma unroll
        for (int ct = 0; ct < 4; ++ct) {
            bhf[ct] = *(const short8*)&sBh[(wc + ct * 16 + m) * ST + quad * 8];
            blf[ct] = *(const short8*)&sBl[(wc + ct * 16 + m) * ST + quad * 8];
        }
        #pragma unroll
        for (int rt = 0; rt < 2; ++rt) {
            short8 ahf = *(const short8*)&sA[(wr + rt * 16 + m) * ST + quad * 8];
            #pragma unroll
            for (int ct = 0; ct < 4; ++ct) {
                acc[rt][ct] = __builtin_amdgcn_mfma_f32_16x16x32_bf16(ahf, bhf[ct], acc[rt][ct], 0, 0, 0);
                acc[rt][ct] = __builtin_amdgcn_mfma_f32_16x16x32_bf16(ahf, blf[ct], acc[rt][ct], 0, 0, 0);
            }
        }
        __syncthreads();
    }

    #pragma unroll
    for (int rt = 0; rt < 2; ++rt) {
        #pragma unroll
        for (int ct = 0; ct < 4; ++ct) {
            int ocol = col0 + wc + ct * 16 + m;
            float bb = bias[ocol];
            #pragma unroll
            for (int reg = 0; reg < 4; ++reg) {
                int orow = row0 + wr + rt * 16 + quad * 4 + reg;
                if (orow >= GN_N) continue;
                Obf[(size_t)orow * ldo + ocol] = f2bf_rne(acc[rt][ct][reg] + bb);
            }
        }
    }
}

// ---------------- CSR build ----------------
__global__ void zero_int(int* p, int n)
{
    int i = blockIdx.x * 256 + threadIdx.x;
    if (i < n) p[i] = 0;
}

__global__ void hist_kernel(const int* __restrict__ dst, int* __restrict__ deg)
{
    int e = blockIdx.x * 256 + threadIdx.x;
    if (e < GN_E) atomicAdd(&deg[dst[e]], 1);
}

__global__ void scan1(const int* __restrict__ deg, int* __restrict__ rp, int* __restrict__ bsums)
{
    __shared__ int s[256];
    int b = blockIdx.x, t = threadIdx.x;
    int i = b * 256 + t;
    int v = (i < GN_N) ? deg[i] : 0;
    s[t] = v;
    __syncthreads();
    for (int off = 1; off < 256; off <<= 1) {
        int x = (t >= off) ? s[t - off] : 0;
        __syncthreads();
        s[t] += x;
        __syncthreads();
    }
    if (i < GN_N) rp[i] = s[t] - v;
    if (t == 255) bsums[b] = s[255];
}

__global__ __launch_bounds__(512) void scan2(int* bsums, int nb)
{
    __shared__ int s[512];
    int t = threadIdx.x;
    int v = (t < nb) ? bsums[t] : 0;
    s[t] = v;
    __syncthreads();
    for (int off = 1; off < 512; off <<= 1) {
        int x = (t >= off) ? s[t - off] : 0;
        __syncthreads();
        s[t] += x;
        __syncthreads();
    }
    if (t < nb) bsums[t] = s[t] - v;
}

__global__ void scan3(const int* __restrict__ bsums, int* __restrict__ rp, int* __restrict__ cursor)
{
    int b = blockIdx.x, t = threadIdx.x;
    int i = b * 256 + t;
    if (i < GN_N) {
        int v = rp[i] + bsums[b];
        rp[i] = v; cursor[i] = v;
    }
    if (i == 0) rp[GN_N] = GN_E;
}

__global__ void scatter_kernel(
    const int* __restrict__ src, const int* __restrict__ dst,
    int* __restrict__ cursor, int* __restrict__ elist)
{
    int e = blockIdx.x * 256 + threadIdx.x;
    if (e >= GN_E) return;
    int d = dst[e];
    int pos = atomicAdd(&cursor[d], 1);
    elist[pos] = src[e];
}

__global__ void bounds_kernel(const int* __restrict__ batch, int* __restrict__ se)
{
    int i = blockIdx.x * 256 + threadIdx.x;
    if (i >= GN_N) return;
    int g = batch[i];
    if (i == 0 || batch[i - 1] != g) se[g] = i;
    if (i == GN_N - 1 || batch[i + 1] != g) se[32 + g] = i + 1;
}

__global__ void cnt_kernel(const int* __restrict__ se, float* __restrict__ cnt)
{
    int g = threadIdx.x;
    if (g < GN_G) cnt[g] = (float)(se[32 + g] - se[g]);
}

// Gbf[N][256] = [K(64) | Q0V0Q1V1..(128) | S(64)] bf16. acc seeds from S;
// out_i = S_i + sum relu(K[i]+Q[j])*V[j] -> bf16 Abf (ald/aoff). 4 nodes/wave,
// 8-edge batch (all loads independent), serial tail for deg>8.
__global__ __launch_bounds__(256, 2) void edge_gather_w(
    const ushort* __restrict__ Gbf, ushort* __restrict__ Abf, int ald, int aoff,
    const int* __restrict__ row_ptr, const int* __restrict__ elist)
{
    int w = threadIdx.x >> 6, c = threadIdx.x & 63;
    int n0 = blockIdx.x * 16 + w * 4;

    float k[4], acc[4];
    int beg[4], end[4];
    #pragma unroll
    for (int j = 0; j < 4; ++j) {
        int node = n0 + j;
        bool ok = node < GN_N;
        int nd = ok ? node : 0;
        beg[j] = row_ptr[nd];
        end[j] = ok ? row_ptr[nd + 1] : beg[j];
        k[j]   = bf2f(Gbf[(size_t)nd * 256 + c]);
        acc[j] = bf2f(Gbf[(size_t)nd * 256 + 192 + c]);
    }
    int s[32];
    #pragma unroll
    for (int j = 0; j < 4; ++j) {
        #pragma unroll
        for (int e = 0; e < 8; ++e) {
            int idx = beg[j] + e;
            s[j * 8 + e] = elist[idx < end[j] ? idx : 0];
        }
    }
    uint qv[32];
    #pragma unroll
    for (int je = 0; je < 32; ++je)
        qv[je] = *(const uint*)&Gbf[(size_t)s[je] * 256 + 64 + 2 * c];
    #pragma unroll
    for (int j = 0; j < 4; ++j) {
        #pragma unroll
        for (int e = 0; e < 8; ++e) {
            if (beg[j] + e < end[j]) {
                uint p = qv[j * 8 + e];
                float gt = k[j] + bf2f((ushort)(p & 0xffffu));
                if (gt > 0.f) acc[j] += gt * bf2f((ushort)(p >> 16));
            }
        }
    }
    #pragma unroll
    for (int j = 0; j < 4; ++j) {
        for (int i = beg[j] + 8; i < end[j]; ++i) {
            int ss = elist[i];
            uint p = *(const uint*)&Gbf[(size_t)ss * 256 + 64 + 2 * c];
            float gt = k[j] + bf2f((ushort)(p & 0xffffu));
            if (gt > 0.f) acc[j] += gt * bf2f((ushort)(p >> 16));
        }
    }
    #pragma unroll
    for (int j = 0; j < 4; ++j)
        if (n0 + j < GN_N) Abf[(size_t)(n0 + j) * ald + aoff + c] = f2bf_rne(acc[j]);
}

// Layer-3: gather + leaky + 16-node LDS reduce + striped run-length atomics.
__global__ __launch_bounds__(256, 2) void edge_gather_pool(
    const ushort* __restrict__ Gbf,
    const int* __restrict__ row_ptr, const int* __restrict__ elist,
    const int* __restrict__ batch,
    float* __restrict__ sums, int c0)
{
    __shared__ float red[16][64];
    __shared__ int gid[16];
    int w = threadIdx.x >> 6, c = threadIdx.x & 63;
    int n0 = blockIdx.x * 16 + w * 4;

    float k[4], acc[4];
    int beg[4], end[4];
    #pragma unroll
    for (int j = 0; j < 4; ++j) {
        int node = n0 + j;
        bool ok = node < GN_N;
        int nd = ok ? node : 0;
        beg[j] = row_ptr[nd];
        end[j] = ok ? row_ptr[nd + 1] : beg[j];
        k[j]   = bf2f(Gbf[(size_t)nd * 256 + c]);
        acc[j] = ok ? bf2f(Gbf[(size_t)nd * 256 + 192 + c]) : 0.f;
    }
    int s[32];
    #pragma unroll
    for (int j = 0; j < 4; ++j) {
        #pragma unroll
        for (int e = 0; e < 8; ++e) {
            int idx = beg[j] + e;
            s[j * 8 + e] = elist[idx < end[j] ? idx : 0];
        }
    }
    uint qv[32];
    #pragma unroll
    for (int je = 0; je < 32; ++je)
        qv[je] = *(const uint*)&Gbf[(size_t)s[je] * 256 + 64 + 2 * c];
    #pragma unroll
    for (int j = 0; j < 4; ++j) {
        #pragma unroll
        for (int e = 0; e < 8; ++e) {
            if (beg[j] + e < end[j]) {
                uint p = qv[j * 8 + e];
                float gt = k[j] + bf2f((ushort)(p & 0xffffu));
                if (gt > 0.f) acc[j] += gt * bf2f((ushort)(p >> 16));
            }
        }
    }
    #pragma unroll
    for (int j = 0; j < 4; ++j) {
        for (int i = beg[j] + 8; i < end[j]; ++i) {
            int ss = elist[i];
            uint p = *(const uint*)&Gbf[(size_t)ss * 256 + 64 + 2 * c];
            float gt = k[j] + bf2f((ushort)(p & 0xffffu));
            if (gt > 0.f) acc[j] += gt * bf2f((ushort)(p >> 16));
        }
    }
    #pragma unroll
    for (int j = 0; j < 4; ++j) {
        float a = acc[j];
        red[w * 4 + j][c] = a > 0.f ? a : 0.01f * a;
    }
    if (c < 4) {
        int node = n0 + c;
        gid[w * 4 + c] = (node < GN_N) ? batch[node] : -1;
    }
    __syncthreads();
    if (w == 0) {
        int stripe = blockIdx.x & 31;
        int i = 0;
        while (i < 16) {
            int gg = gid[i];
            float sum = 0.f;
            int j = i;
            while (j < 16 && gid[j] == gg) { sum += red[j][c]; ++j; }
            if (gg >= 0) atomicAdd(&sums[(size_t)(stripe * GN_G + gg) * 256 + c0 + c], sum);
            i = j;
        }
    }
}

__global__ void zero_sums(float* sums)
{
    int i = blockIdx.x * 256 + threadIdx.x;
    if (i < 32 * GN_G * 256) sums[i] = 0.0f;
}

// One block per graph: reduce 32 stripes; Pl = sums[g]/cnt[g];
// Pg = Pl @ Wl3 + bl3; BN-MLP chain.
__global__ __launch_bounds__(256) void mlp_kernel(
    const float* __restrict__ sums, const float* __restrict__ cnt,
    const float* __restrict__ Wl3, const float* __restrict__ bl3,
    const float* __restrict__ W1, const float* __restrict__ b1,
    const float* __restrict__ Wh, const float* __restrict__ bh,
    const float* __restrict__ Wo, const float* __restrict__ bo,
    const float* __restrict__ gamma, const float* __restrict__ beta,
    const float* __restrict__ mean, const float* __restrict__ var,
    float* __restrict__ out)
{
    __shared__ float sp[256];
    __shared__ float pg[256];
    __shared__ float h0[64], h1[64];
    const int g = blockIdx.x;
    const int t = threadIdx.x;
    const float inv = 1.0f / fmaxf(cnt[g], 1.0f);

    {
        float acc = 0.f;
        #pragma unroll 8
        for (int st = 0; st < 32; ++st)
            acc += sums[(size_t)(st * GN_G + g) * 256 + t];
        sp[t] = acc * inv;
    }
    __syncthreads();

    {
        float a0 = 0.f, a1 = 0.f, a2 = 0.f, a3 = 0.f;
        #pragma unroll 4
        for (int k = 0; k < 256; k += 4) {
            a0 += sp[k + 0] * Wl3[(k + 0) * 256 + t];
            a1 += sp[k + 1] * Wl3[(k + 1) * 256 + t];
            a2 += sp[k + 2] * Wl3[(k + 2) * 256 + t];
            a3 += sp[k + 3] * Wl3[(k + 3) * 256 + t];
        }
        pg[t] = bl3[t] + ((a0 + a1) + (a2 + a3));
    }
    __syncthreads();

    if (t < 64) {
        float a0 = 0.f, a1 = 0.f, a2 = 0.f, a3 = 0.f;
        #pragma unroll 4
        for (int k = 0; k < 256; k += 4) {
            a0 += pg[k + 0] * W1[(k + 0) * 64 + t];
            a1 += pg[k + 1] * W1[(k + 1) * 64 + t];
            a2 += pg[k + 2] * W1[(k + 2) * 64 + t];
            a3 += pg[k + 3] * W1[(k + 3) * 64 + t];
        }
        float acc = b1[t] + ((a0 + a1) + (a2 + a3));
        float sc = gamma[t] * rsqrtf(var[t] + 1e-5f);
        acc = (acc - mean[t]) * sc + beta[t];
        h0[t] = fmaxf(acc, 0.0f);
    }
    __syncthreads();

    for (int L = 0; L < 3; ++L) {
        const float* W  = Wh + L * 64 * 64;
        const float* hin  = (L & 1) ? h1 : h0;
        float*       hout = (L & 1) ? h0 : h1;
        if (t < 64) {
            const float* ga = gamma + (L + 1) * 64;
            const float* be = beta  + (L + 1) * 64;
            const float* me = mean  + (L + 1) * 64;
            const float* va = var   + (L + 1) * 64;
            float a0 = 0.f, a1 = 0.f, a2 = 0.f, a3 = 0.f;
            #pragma unroll 4
            for (int k = 0; k < 64; k += 4) {
                a0 += hin[k + 0] * W[(k + 0) * 64 + t];
                a1 += hin[k + 1] * W[(k + 1) * 64 + t];
                a2 += hin[k + 2] * W[(k + 2) * 64 + t];
                a3 += hin[k + 3] * W[(k + 3) * 64 + t];
            }
            float acc = (bh + L * 64)[t] + ((a0 + a1) + (a2 + a3));
            float sc = ga[t] * rsqrtf(va[t] + 1e-5f);
            acc = (acc - me[t]) * sc + be[t];
            hout[t] = fmaxf(acc, 0.0f);
        }
        __syncthreads();
    }

    if (t < 8) {
        const float* hf = h1;
        float acc = bo[t];
        for (int k = 0; k < 64; ++k) acc += hf[k] * Wo[k * 8 + t];
        out[g * 8 + t] = acc;
    }
}

extern "C" void kernel_launch(void* const* d_in, const int* in_sizes, int n_in,
                              void* d_out, int out_size, void* d_ws, size_t ws_size,
                              hipStream_t stream)
{
    const int N = GN_N, E = GN_E;
    const float* x          = (const float*)d_in[0];
    const int*   edge_index = (const int*)d_in[1];
    const int*   batch      = (const int*)d_in[2];
    const int*   src = edge_index;
    const int*   dst = edge_index + E;
    auto F = [&](int i) { return (const float*)d_in[i]; };

    // ---- workspace layout ----
    float* ws    = (float*)d_ws;
    float* sums  = ws;                          // 32 stripes x 32 x 256
    float* cnt   = sums + 32 * GN_G * 256;      // 32
    float* bcat  = cnt + GN_G;                  // 7 x 256
    ushort* Whi  = (ushort*)(bcat + 1792);
    ushort* Wlo  = Whi + W_TOTAL;
    ushort* xbf  = Wlo + W_TOTAL;               // N x 128 bf16
    ushort* hAbf = xbf + (size_t)N * 128;       // N x 64 bf16
    ushort* hBbf = hAbf + (size_t)N * 64;       // N x 128 bf16
    ushort* Gbf  = hBbf + (size_t)N * 128;      // N x 256 bf16 [K|QV|S]
    ushort* Abf  = Gbf + (size_t)N * 256;       // N x 128 bf16 (pre-Wl acts)
    int* deg     = (int*)(Abf + (size_t)N * 128);
    int* cursor  = deg + N;
    int* row_ptr = cursor + N;                  // N+1
    int* elist   = row_ptr + (N + 1);           // E
    int* bsums   = elist + E;                   // 512
    int* se      = bsums + 512;                 // 64

    size_t need = (size_t)((char*)(se + 64) - (char*)ws);
    if (ws_size < need) return;

    // ---- CSR build + graph bounds ----
    const int eb = (E + 255) / 256;
    const int nb = (N + 255) / 256;
    zero_int<<<nb, 256, 0, stream>>>(deg, N);
    zero_int<<<1, 256, 0, stream>>>(se, 64);
    hist_kernel<<<eb, 256, 0, stream>>>(dst, deg);
    scan1<<<nb, 256, 0, stream>>>(deg, row_ptr, bsums);
    scan2<<<1, 512, 0, stream>>>(bsums, nb);
    scan3<<<nb, 256, 0, stream>>>(bsums, row_ptr, cursor);
    scatter_kernel<<<eb, 256, 0, stream>>>(src, dst, cursor, elist);
    bounds_kernel<<<nb, 256, 0, stream>>>(batch, se);
    cnt_kernel<<<1, 64, 0, stream>>>(se, cnt);

    // ---- weight + input pre-conversion ----
    WSrc S;
    for (int l = 0; l < 3; ++l) {
        int base = 3 + l * 10;
        for (int g = 0; g < 4; ++g) S.Wg[l][g] = F(base + g);
        for (int g = 0; g < 4; ++g) S.bg[l][g] = F(base + 4 + g);
    }
    S.Wl[0] = F(11); S.Wl[1] = F(21);
    wconv<<<(W_TOTAL + 1792 + 255) / 256, 256, 0, stream>>>(S, Whi, Wlo, bcat);
    aconv<<<(N * 16 + 255) / 256, 256, 0, stream>>>(x, xbf);

    zero_sums<<<(32 * GN_G * 256 + 255) / 256, 256, 0, stream>>>(sums);

    const int rb = (N + 127) / 128;
    const int gatherBlocks = (N + 15) / 16;

    // ---- layer 1 ----
    gemm2<128, 0><<<dim3(rb, 2), 512, 0, stream>>>(
        xbf, 128, Whi, Wlo, bcat, Gbf, 256, 128);
    edge_gather_w<<<gatherBlocks, 256, 0, stream>>>(Gbf, Abf, 64, 0, row_ptr, elist);
    gemm2<64, 2><<<dim3(rb, 1), 256, 0, stream>>>(
        Abf, 64, Whi + WOFF_WL1, Wlo + WOFF_WL1, F(12), hAbf, 64, 64);

    // ---- layer 2 (2 chunks of gates, then one Wl2) ----
    for (int ch = 0; ch < 2; ++ch) {
        size_t go = WOFF_L2 + (size_t)ch * 16384;
        gemm2<128, 0><<<dim3(rb, 2), 512, 0, stream>>>(
            hAbf, 64, Whi + go, Wlo + go, bcat + (1 + ch) * 256, Gbf, 256, 64);
        edge_gather_w<<<gatherBlocks, 256, 0, stream>>>(
            Gbf, Abf, 128, ch * 64, row_ptr, elist);
    }
    gemm2<128, 2><<<dim3(rb, 1), 512, 0, stream>>>(
        Abf, 128, Whi + WOFF_WL2, Wlo + WOFF_WL2, F(22), hBbf, 128, 128);

    // ---- layer 3 (4 chunks, fused pool) ----
    for (int ch = 0; ch < 4; ++ch) {
        size_t go = WOFF_L3 + (size_t)ch * 32768;
        gemm2<128, 0><<<dim3(rb, 2), 512, 0, stream>>>(
            hBbf, 128, Whi + go, Wlo + go, bcat + (3 + ch) * 256, Gbf, 256, 128);
        edge_gather_pool<<<gatherBlocks, 256, 0, stream>>>(
            Gbf, row_ptr, elist, batch, sums, ch * 64);
    }

    mlp_kernel<<<GN_G, 256, 0, stream>>>(sums, cnt, F(31), F(32),
                                         F(33), F(34), F(35), F(36), F(37), F(38),
                                         F(39), F(40), F(41), F(42),
                                         (float*)d_out);
}